// Round 8
// baseline (1472.655 us; speedup 1.0000x reference)
//
#include <hip/hip_runtime.h>
#include <hip/hip_bf16.h>

// Decoder_70033736728716 v5: reg-streamed weights, nt stores, no hot-loop asm.
//
// R7 post-mortem: v1/v3/v4 all pinned at ~15 GB/s/CU weight supply (2.1us/kc
// = one full memory latency per frame). Suspects: (1) inline-asm waitcnt with
// memory clobber forcing per-kc drains; (2) y write-allocate (1.4MB/step/XCD
// scattered 4B stores) thrashing the 512KB weight set out of L2 (FETCH 12x
// retention ideal; 5.1GB demand REQUIRES L2 service). v5: weights load
// straight into VGPRs as MFMA B-frags (plain dwordx4, compiler counted waits,
// 4-slot static-index pipeline, 2-frame lookahead, gates split r,z | gh,gi
// for reg budget); ALL y stores nontemporal; pred staged in LDS and stored by
// all 8 waves at step end; __syncthreads only.

typedef __bf16 bf16x8 __attribute__((ext_vector_type(8)));
typedef float  f32x16 __attribute__((ext_vector_type(16)));

#define MFMA32(a,b,c) __builtin_amdgcn_mfma_f32_32x32x16_bf16((a),(b),(c),0,0,0)

static constexpr int A_DIM = 21;

// ws layout (bytes) — unchanged from v4
static constexpr size_t O_W1F   = 0;                       // 256x128 frag order
static constexpr size_t O_W2F   = O_W1F + 256*128*2;       // 256x256
static constexpr size_t O_ST1   = O_W2F + 256*256*2;       // step-1 [w][kc][3]x1KB
static constexpr size_t O_WMN   = O_ST1 + 8*16*3*1024;     // main [w][kc][4]x1KB
static constexpr size_t O_WDF   = O_WMN + 8*16*4*1024;     // Wd frag [kc]x1KB
static constexpr size_t O_BMAIN = O_WDF + 16*1024;         // 1024 f32
static constexpr size_t O_GI1   = O_BMAIN + 1024*4;        // 768 f32

// ---------------- prep kernels (unchanged from v4) ----------------

__global__ void prep_frag(const float* __restrict__ src, __bf16* __restrict__ dst,
                          int SR, int SC, int NF, int NCH) {
  int total = NF * NCH * 512;
  for (int i = blockIdx.x * blockDim.x + threadIdx.x; i < total;
       i += gridDim.x * blockDim.x) {
    int fragid = i >> 9, within = i & 511;
    int lane = within >> 3, j = within & 7;
    int nf = fragid / NCH, kc = fragid - nf * NCH;
    int n = nf * 32 + (lane & 31);
    int k = kc * 16 + (lane >> 5) * 8 + j;
    float v = (n < SR && k < SC) ? src[n * SC + k] : 0.f;
    dst[i] = (__bf16)v;
  }
}

__global__ void prep_st1(const float* __restrict__ Whh, __bf16* __restrict__ dst) {
  int total = 8 * 16 * 3 * 512;
  for (int i = blockIdx.x * blockDim.x + threadIdx.x; i < total;
       i += gridDim.x * blockDim.x) {
    int j = i & 7, lane = (i >> 3) & 63;
    int slice = i >> 9;
    int g = slice % 3, kc = (slice / 3) & 15, w = slice / 48;
    int n = g * 256 + w * 32 + (lane & 31);
    int k = kc * 16 + (lane >> 5) * 8 + j;
    dst[i] = (__bf16)Whh[n * 256 + k];
  }
}

__global__ void prep_main(const float* __restrict__ Whh, const float* __restrict__ Wih,
                          const float* __restrict__ Wd, __bf16* __restrict__ dst) {
  int total = 8 * 16 * 4 * 512;
  for (int i = blockIdx.x * blockDim.x + threadIdx.x; i < total;
       i += gridDim.x * blockDim.x) {
    int j = i & 7, lane = (i >> 3) & 63;
    int slice = i >> 9;
    int g = slice & 3, kc = (slice >> 2) & 15, w = slice >> 6;
    int k = kc * 16 + (lane >> 5) * 8 + j;
    int n = g * 256 + w * 32 + (lane & 31);
    float v = 0.f;
    if (n < 768) v = Whh[n * 256 + k];
    if (n < 512 || n >= 768) {
      int nn = (n < 512) ? n : (n - 256);
      float d = 0.f;
      #pragma unroll
      for (int q = 0; q < A_DIM; ++q) d += Wih[nn * A_DIM + q] * Wd[q * 256 + k];
      v += d;
    }
    dst[i] = (__bf16)v;
  }
}

__global__ void prep_bias(const float* __restrict__ Wih, const float* __restrict__ bih,
                          const float* __restrict__ bhh, const float* __restrict__ bd,
                          float* __restrict__ bmain, float* __restrict__ gi1c) {
  int i = blockIdx.x * blockDim.x + threadIdx.x;
  if (i < 1024) {
    float bm;
    if (i < 512) {
      float d = 0.f;
      #pragma unroll
      for (int q = 0; q < A_DIM; ++q) d += Wih[i * A_DIM + q] * bd[q];
      bm = bhh[i] + bih[i] + d;
    } else if (i < 768) {
      bm = bhh[i];
    } else {
      int nn = i - 256;
      float d = 0.f;
      #pragma unroll
      for (int q = 0; q < A_DIM; ++q) d += Wih[nn * A_DIM + q] * bd[q];
      bm = bih[nn] + d;
    }
    bmain[i] = bm;
  }
  if (i < 768) {
    float s = 32.f * Wih[i * A_DIM + 0];
    #pragma unroll
    for (int q = 1; q < A_DIM; ++q) s -= 32.f * Wih[i * A_DIM + q];
    gi1c[i] = s + bih[i];
  }
}

// ---------------- device helpers ----------------

__device__ __forceinline__ bf16x8 lds_frag(const __bf16* base, int rowBytes,
                                           int row, int kb) {
  return *(const bf16x8*)((const char*)base + row * rowBytes +
                          (kb ^ ((row & 7) << 4)));
}

__device__ __forceinline__ void gru_gate(const f32x16& ar, const f32x16& az,
                                         const f32x16& ah, const f32x16& ai,
                                         f32x16& hr) {
  #pragma unroll
  for (int g = 0; g < 16; ++g) {
    float r = __builtin_amdgcn_rcpf(1.f + __builtin_amdgcn_exp2f(ar[g] * -1.442695041f));
    float z = __builtin_amdgcn_rcpf(1.f + __builtin_amdgcn_exp2f(az[g] * -1.442695041f));
    float pre = ai[g] + r * ah[g];
    float e = __builtin_amdgcn_exp2f(pre * 2.885390082f);
    float n = 1.f - 2.f * __builtin_amdgcn_rcpf(e + 1.f);
    hr[g] = n + z * (hr[g] - n);
  }
}

__device__ __forceinline__ void write_h(__bf16* hl, int c, int hfv,
                                        const f32x16& hr0, const f32x16& hr1) {
  #pragma unroll
  for (int g = 0; g < 16; ++g) {
    int pat = (g & 3) + 8 * (g >> 2) + 4 * hfv;
    int sw = (2 * c) ^ ((pat & 7) << 4);
    *(__bf16*)((char*)hl + pat * 512 + sw)        = (__bf16)hr0[g];
    *(__bf16*)((char*)hl + (32 + pat) * 512 + sw) = (__bf16)hr1[g];
  }
}

// ---------------- main persistent kernel ----------------
// grid 256 x 512 (8 waves). Wave w owns gate/h-cols [32w,32w+32).
// LDS: h 32K + h1 32K + lat 16K + wd 16K + pred 10.5K = 106.5KB -> 1 block/CU.
__global__ __launch_bounds__(512, 2) void decoder_main(
    const float* __restrict__ latent, const float* __restrict__ b1,
    const float* __restrict__ b2, const float* __restrict__ bhh,
    const float* __restrict__ bd, const float* __restrict__ gi1c,
    const float* __restrict__ bmain,
    const __bf16* __restrict__ W1f, const __bf16* __restrict__ W2f,
    const __bf16* __restrict__ St1, const __bf16* __restrict__ Wmn,
    const __bf16* __restrict__ Wdf, float* __restrict__ y) {
  __shared__ __attribute__((aligned(16))) __bf16 h_lds[64 * 256];
  __shared__ __attribute__((aligned(16))) __bf16 h1_lds[64 * 256];
  __shared__ __attribute__((aligned(16))) __bf16 lat_lds[64 * 128];
  __shared__ __attribute__((aligned(16))) char wd_lds[16 * 1024];
  __shared__ float pred_lds[2][64 * A_DIM];

  const int tid = threadIdx.x;
  const int w = tid >> 6;
  const int l = tid & 63;
  const int lc = l & 31;
  const int hfv = l >> 5;
  const int b0 = blockIdx.x * 64;
  const int c = w * 32 + lc;
  const int ph = (blockIdx.x >> 3) & 15;   // de-phase (kept; harmless)

  // y[:,0,:] = start (nontemporal: keep y out of L2)
  for (int i = tid; i < 64 * A_DIM; i += 512) {
    int r = i / A_DIM, a = i - r * A_DIM;
    __builtin_nontemporal_store((a == 0) ? 32.f : -32.f,
                                &y[(size_t)(b0 + r) * 840 + a]);
  }

  // stage latent tile (fp32 -> bf16, swizzled rowBytes=256)
  for (int i = tid; i < 64 * 32; i += 512) {
    int r = i >> 5, c4 = i & 31;
    const float4 v = *(const float4*)(latent + (size_t)(b0 + r) * 128 + c4 * 4);
    __bf16* q = (__bf16*)((char*)lat_lds + r * 256 + ((c4 * 8) ^ ((r & 7) << 4)));
    q[0] = (__bf16)v.x; q[1] = (__bf16)v.y; q[2] = (__bf16)v.z; q[3] = (__bf16)v.w;
  }

  // Wd -> resident LDS via regs (wave w handles slices 2w, 2w+1)
  {
    bf16x8 v0 = *(const bf16x8*)((const char*)Wdf + (w * 2 + 0) * 1024 + (size_t)l * 16);
    bf16x8 v1 = *(const bf16x8*)((const char*)Wdf + (w * 2 + 1) * 1024 + (size_t)l * 16);
    *(bf16x8*)(wd_lds + (w * 2 + 0) * 1024 + (size_t)l * 16) = v0;
    *(bf16x8*)(wd_lds + (w * 2 + 1) * 1024 + (size_t)l * 16) = v1;
  }
  __syncthreads();

  const bf16x8* W1v = (const bf16x8*)W1f;
  const bf16x8* W2v = (const bf16x8*)W2f;

  // ---- GEMM1: h1 = relu(latent @ W1^T + b1) ----
  f32x16 acc0, acc1;
  {
    const float bb = b1[c];
    #pragma unroll
    for (int i = 0; i < 16; ++i) { acc0[i] = bb; acc1[i] = bb; }
  }
  #pragma unroll
  for (int kc = 0; kc < 8; ++kc) {
    bf16x8 a0 = lds_frag(lat_lds, 256, lc, kc * 32 + hfv * 16);
    bf16x8 a1 = lds_frag(lat_lds, 256, 32 + lc, kc * 32 + hfv * 16);
    bf16x8 bw = W1v[(w * 8 + kc) * 64 + l];
    acc0 = MFMA32(a0, bw, acc0);
    acc1 = MFMA32(a1, bw, acc1);
  }
  #pragma unroll
  for (int g = 0; g < 16; ++g) {
    int pat = (g & 3) + 8 * (g >> 2) + 4 * hfv;
    int sw = (2 * c) ^ ((pat & 7) << 4);
    float v0 = acc0[g] > 0.f ? acc0[g] : 0.f;
    float v1 = acc1[g] > 0.f ? acc1[g] : 0.f;
    *(__bf16*)((char*)h1_lds + pat * 512 + sw)        = (__bf16)v0;
    *(__bf16*)((char*)h1_lds + (32 + pat) * 512 + sw) = (__bf16)v1;
  }
  __syncthreads();

  // ---- GEMM2: h0 = h1 @ W2^T + b2 ----
  f32x16 hr0, hr1;
  {
    const float bb = b2[c];
    #pragma unroll
    for (int i = 0; i < 16; ++i) { hr0[i] = bb; hr1[i] = bb; }
  }
  #pragma unroll
  for (int kc = 0; kc < 16; ++kc) {
    bf16x8 a0 = lds_frag(h1_lds, 512, lc, kc * 32 + hfv * 16);
    bf16x8 a1 = lds_frag(h1_lds, 512, 32 + lc, kc * 32 + hfv * 16);
    bf16x8 bw = W2v[(w * 16 + kc) * 64 + l];
    hr0 = MFMA32(a0, bw, hr0);
    hr1 = MFMA32(a1, bw, hr1);
  }
  write_h(h_lds, c, hfv, hr0, hr1);
  __syncthreads();

  // per-lane bias constants
  const float i_r1 = bhh[c] + gi1c[c];
  const float i_z1 = bhh[256 + c] + gi1c[256 + c];
  const float i_h1 = bhh[512 + c];
  const float i_n1 = gi1c[512 + c];
  const float i_rm = bmain[c];
  const float i_zm = bmain[256 + c];
  const float i_hm = bmain[512 + c];
  const float i_nm = bmain[768 + c];
  const float pb = (lc < A_DIM) ? bd[lc] : 0.f;

  const char* sW1 = (const char*)St1 + w * 49152 + (size_t)l * 16;
  const char* sW  = (const char*)Wmn + w * 65536 + (size_t)l * 16;
  #define S1F(kc) ((const bf16x8*)(sW1 + (((kc) + ph) & 15) * 3072))
  #define SMF(kc) ((const bf16x8*)(sW  + (((kc) + ph) & 15) * 4096))

  f32x16 aR0, aR1, aZ0, aZ1, aH0, aH1, aI0, aI1, pacc;
  bf16x8 wA[4][2], wB[4][2];   // static-indexed 4-slot pipelines (rule #20)

  // ======== step 1: x = start (gi const); stream pure Whh ========
  // pass A: r,z
  #pragma unroll
  for (int i = 0; i < 16; ++i) { aR0[i] = i_r1; aR1[i] = i_r1; aZ0[i] = i_z1; aZ1[i] = i_z1; }
  wA[0][0] = S1F(0)[0];  wA[0][1] = S1F(0)[64];
  wA[1][0] = S1F(1)[0];  wA[1][1] = S1F(1)[64];
  #pragma unroll
  for (int kc = 0; kc < 16; ++kc) {
    if (kc < 14) {
      wA[(kc + 2) & 3][0] = S1F(kc + 2)[0];
      wA[(kc + 2) & 3][1] = S1F(kc + 2)[64];
    } else {                    // prefetch pass-B (h-gate) frames 0,1
      wB[kc - 14][0] = S1F(kc - 14)[128];
    }
    const int kcp = (kc + ph) & 15;
    bf16x8 a0 = lds_frag(h_lds, 512, lc, kcp * 32 + hfv * 16);
    bf16x8 a1 = lds_frag(h_lds, 512, 32 + lc, kcp * 32 + hfv * 16);
    aR0 = MFMA32(a0, wA[kc & 3][0], aR0); aR1 = MFMA32(a1, wA[kc & 3][0], aR1);
    aZ0 = MFMA32(a0, wA[kc & 3][1], aZ0); aZ1 = MFMA32(a1, wA[kc & 3][1], aZ1);
  }
  // pass B: gh (gi = const)
  #pragma unroll
  for (int i = 0; i < 16; ++i) { aH0[i] = i_h1; aH1[i] = i_h1; aI0[i] = i_n1; aI1[i] = i_n1; }
  #pragma unroll
  for (int kc = 0; kc < 16; ++kc) {
    if (kc < 14) {
      wB[(kc + 2) & 3][0] = S1F(kc + 2)[128];
    } else {                    // prefetch main pass-A frames 0,1
      wA[kc - 14][0] = SMF(kc - 14)[0];
      wA[kc - 14][1] = SMF(kc - 14)[64];
    }
    const int kcp = (kc + ph) & 15;
    bf16x8 a0 = lds_frag(h_lds, 512, lc, kcp * 32 + hfv * 16);
    bf16x8 a1 = lds_frag(h_lds, 512, 32 + lc, kcp * 32 + hfv * 16);
    aH0 = MFMA32(a0, wB[kc & 3][0], aH0); aH1 = MFMA32(a1, wB[kc & 3][0], aH1);
  }
  gru_gate(aR0, aZ0, aH0, aI0, hr0);
  gru_gate(aR1, aZ1, aH1, aI1, hr1);
  __syncthreads();
  write_h(h_lds, c, hfv, hr0, hr1);
  __syncthreads();

  // ======== steps 2..39: fused stream in regs ========
  #pragma unroll 1
  for (int t = 2; t <= 39; ++t) {
    // pass A: r,z (slices g0,g1)
    #pragma unroll
    for (int i = 0; i < 16; ++i) { aR0[i] = i_rm; aR1[i] = i_rm; aZ0[i] = i_zm; aZ1[i] = i_zm; }
    #pragma unroll
    for (int kc = 0; kc < 16; ++kc) {
      if (kc < 14) {
        wA[(kc + 2) & 3][0] = SMF(kc + 2)[0];
        wA[(kc + 2) & 3][1] = SMF(kc + 2)[64];
      } else {                  // prefetch pass-B frames 0,1
        wB[kc - 14][0] = SMF(kc - 14)[128];
        wB[kc - 14][1] = SMF(kc - 14)[192];
      }
      const int kcp = (kc + ph) & 15;
      bf16x8 a0 = lds_frag(h_lds, 512, lc, kcp * 32 + hfv * 16);
      bf16x8 a1 = lds_frag(h_lds, 512, 32 + lc, kcp * 32 + hfv * 16);
      aR0 = MFMA32(a0, wA[kc & 3][0], aR0); aR1 = MFMA32(a1, wA[kc & 3][0], aR1);
      aZ0 = MFMA32(a0, wA[kc & 3][1], aZ0); aZ1 = MFMA32(a1, wA[kc & 3][1], aZ1);
    }
    // pass B: gh,gi (+ overlapped pred(t-1) on waves 0/1)
    #pragma unroll
    for (int i = 0; i < 16; ++i) { aH0[i] = i_hm; aH1[i] = i_hm; aI0[i] = i_nm; aI1[i] = i_nm; pacc[i] = pb; }
    #pragma unroll
    for (int kc = 0; kc < 16; ++kc) {
      if (kc < 14) {
        wB[(kc + 2) & 3][0] = SMF(kc + 2)[128];
        wB[(kc + 2) & 3][1] = SMF(kc + 2)[192];
      } else {                  // prefetch NEXT step pass-A frames 0,1
        wA[kc - 14][0] = SMF(kc - 14)[0];
        wA[kc - 14][1] = SMF(kc - 14)[64];
      }
      const int kcp = (kc + ph) & 15;
      bf16x8 a0 = lds_frag(h_lds, 512, lc, kcp * 32 + hfv * 16);
      bf16x8 a1 = lds_frag(h_lds, 512, 32 + lc, kcp * 32 + hfv * 16);
      aH0 = MFMA32(a0, wB[kc & 3][0], aH0); aH1 = MFMA32(a1, wB[kc & 3][0], aH1);
      aI0 = MFMA32(a0, wB[kc & 3][1], aI0); aI1 = MFMA32(a1, wB[kc & 3][1], aI1);
      if (w < 2) {
        bf16x8 bp = *(const bf16x8*)(wd_lds + kcp * 1024 + (size_t)l * 16);
        pacc = MFMA32(w ? a1 : a0, bp, pacc);
      }
    }
    gru_gate(aR0, aZ0, aH0, aI0, hr0);
    gru_gate(aR1, aZ1, aH1, aI1, hr1);
    // stage pred(t-1) (fp32, exact) for distributed store next step
    if (w < 2 && lc < A_DIM) {
      #pragma unroll
      for (int g = 0; g < 16; ++g) {
        int pat = (g & 3) + 8 * (g >> 2) + 4 * hfv;
        pred_lds[(t - 1) & 1][(32 * w + pat) * A_DIM + lc] = pacc[g];
      }
    }
    // all 8 waves store pred(t-2): 3 nt stores/wave, drained by the barrier
    if (t >= 3) {
      const float* ps = &pred_lds[t & 1][w * 8 * A_DIM];
      #pragma unroll
      for (int rep = 0; rep < 3; ++rep) {
        int idx = rep * 64 + l;
        if (idx < 8 * A_DIM) {
          int rr = idx / A_DIM, cc = idx - rr * A_DIM;
          __builtin_nontemporal_store(
              ps[idx], &y[(size_t)(b0 + 8 * w + rr) * 840 + (size_t)(t - 2) * 21 + cc]);
        }
      }
    }
    __syncthreads();
    write_h(h_lds, c, hfv, hr0, hr1);
    __syncthreads();
  }

  // ---- tail: store pred(38); compute+store pred(39) ----
  {
    const float* ps = &pred_lds[0][w * 8 * A_DIM];   // pred(38) in buf 0
    #pragma unroll
    for (int rep = 0; rep < 3; ++rep) {
      int idx = rep * 64 + l;
      if (idx < 8 * A_DIM) {
        int rr = idx / A_DIM, cc = idx - rr * A_DIM;
        __builtin_nontemporal_store(
            ps[idx], &y[(size_t)(b0 + 8 * w + rr) * 840 + (size_t)38 * 21 + cc]);
      }
    }
  }
  if (w < 2) {
    #pragma unroll
    for (int i = 0; i < 16; ++i) pacc[i] = pb;
    #pragma unroll
    for (int kc = 0; kc < 16; ++kc) {
      bf16x8 a = lds_frag(h_lds, 512, 32 * w + lc, kc * 32 + hfv * 16);
      bf16x8 bp = *(const bf16x8*)(wd_lds + kc * 1024 + (size_t)l * 16);
      pacc = MFMA32(a, bp, pacc);
    }
    if (lc < A_DIM) {
      #pragma unroll
      for (int g = 0; g < 16; ++g) {
        int pat = (g & 3) + 8 * (g >> 2) + 4 * hfv;
        __builtin_nontemporal_store(
            pacc[g], &y[(size_t)(b0 + 32 * w + pat) * 840 + (size_t)39 * 21 + lc]);
      }
    }
  }
  #undef S1F
  #undef SMF
}

extern "C" void kernel_launch(void* const* d_in, const int* in_sizes, int n_in,
                              void* d_out, int out_size, void* d_ws, size_t ws_size,
                              hipStream_t stream) {
  const float* latent = (const float*)d_in[0];
  const float* W1 = (const float*)d_in[1];
  const float* b1 = (const float*)d_in[2];
  const float* W2 = (const float*)d_in[3];
  const float* b2 = (const float*)d_in[4];
  const float* Wih = (const float*)d_in[5];
  const float* Whh = (const float*)d_in[6];
  const float* bih = (const float*)d_in[7];
  const float* bhh = (const float*)d_in[8];
  const float* Wd = (const float*)d_in[9];
  const float* bd = (const float*)d_in[10];
  float* y = (float*)d_out;
  char* ws = (char*)d_ws;

  __bf16* W1f = (__bf16*)(ws + O_W1F);
  __bf16* W2f = (__bf16*)(ws + O_W2F);
  __bf16* St1 = (__bf16*)(ws + O_ST1);
  __bf16* Wmn = (__bf16*)(ws + O_WMN);
  __bf16* Wdf = (__bf16*)(ws + O_WDF);
  float* bmain = (float*)(ws + O_BMAIN);
  float* gi1c = (float*)(ws + O_GI1);

  prep_frag<<<128, 256, 0, stream>>>(W1, W1f, 256, 128, 8, 8);
  prep_frag<<<256, 256, 0, stream>>>(W2, W2f, 256, 256, 8, 16);
  prep_frag<<<32, 256, 0, stream>>>(Wd, Wdf, 21, 256, 1, 16);
  prep_st1<<<512, 256, 0, stream>>>(Whh, St1);
  prep_main<<<1024, 256, 0, stream>>>(Whh, Wih, Wd, Wmn);
  prep_bias<<<4, 256, 0, stream>>>(Wih, bih, bhh, bd, bmain, gi1c);

  decoder_main<<<256, 512, 0, stream>>>(latent, b1, b2, bhh, bd, gi1c, bmain,
                                        W1f, W2f, St1, Wmn, Wdf, y);
}